// Round 1
// baseline (6021.701 us; speedup 1.0000x reference)
//
#include <hip/hip_runtime.h>
#include <hip/hip_bf16.h>

// LSTM T=512 B=256 NP=34 H=512 NT=16.
// Plan: 16 groups (16 batches each) x 16 blocks (32 h-cols each, all 4 gates).
// W_hh slice + W_ih slice resident in LDS as bf16, K = 512(h)+34(x)+pad = 576.
// Per step: group exchanges h via agent-scope atomics in global ws + counter barrier.
#define TT 512
#define BT 256
#define NP 34
#define HH 512
#define GB 16
#define GN 16

typedef short bf16x8 __attribute__((ext_vector_type(8)));
typedef float f32x4 __attribute__((ext_vector_type(4)));

static __device__ __forceinline__ unsigned short f2bf(float x) {
  unsigned int u = __float_as_uint(x);
  unsigned int r = (u + 0x7fffu + ((u >> 16) & 1u)) >> 16;
  return (unsigned short)r;
}

// LDS map (163840 B total, dynamic):
//   [0, 147456)        W slice bf16 [128 rows][576], 16B-chunk swizzle: phys_chunk = c ^ (r&7)
//   [147456, 163840)   phase-aliased: h-stage bf16 [16][512] (same swizzle) during MFMA;
//                      gates f32 [128][20] during epilogue.
__global__ void __launch_bounds__(256, 1) lstm_coop(
    const float* __restrict__ Whh, const float* __restrict__ Wih,
    const float* __restrict__ bih, const float* __restrict__ bhh,
    const unsigned short* __restrict__ Ax,  // [T][256][64] bf16 bits: [points(34), 0...]
    unsigned short* hs,                     // [T][256][512] bf16 bits
    unsigned int* ctr)                      // [16] counters, stride 16 u32
{
  extern __shared__ char smem[];
  unsigned short* Wl = (unsigned short*)smem;
  unsigned short* hstage = (unsigned short*)(smem + 147456);
  float* gatesL = (float*)(smem + 147456);

  const int tid = threadIdx.x;
  const int g = blockIdx.x & 15;   // group
  const int n = blockIdx.x >> 4;   // block-in-group -> h-cols [n*32, n*32+32)
  const int bbase = g * 16;        // batch base

  // ---- init resident W slice (swizzled) ----
  for (int idx = tid; idx < 128 * 576; idx += 256) {
    int r = idx / 576, k = idx - r * 576;
    int grow = (r >> 5) * 512 + n * 32 + (r & 31);  // gate q=r>>5 (i,f,g,o), hcol j=r&31
    float v = 0.f;
    if (k < 512) v = Whh[(size_t)grow * 512 + k];
    else if (k < 546) v = Wih[grow * 34 + (k - 512)];
    int c = k >> 3, within = k & 7;
    Wl[r * 576 + ((c ^ (r & 7)) << 3) + within] = f2bf(v);
  }
  // epilogue cell assignment: thread -> (batch em, hcols ej, ej+1); biases exact in regs
  const int em = tid >> 4;
  const int ej = (tid & 15) << 1;
  float bias[4][2];
#pragma unroll
  for (int q = 0; q < 4; ++q) {
    int gr = q * 512 + n * 32 + ej;
    bias[q][0] = bih[gr] + bhh[gr];
    bias[q][1] = bih[gr + 1] + bhh[gr + 1];
  }
  const int lane = tid & 63;
  const int w = tid >> 6;
  const int m = lane & 15;   // A: batch row; B/D: col within tile
  const int ko = lane >> 4;
  const int r0 = 32 * w + m; // wave w covers W rows [32w,32w+32) = gate q=w
  float c0s = 0.f, c1s = 0.f;
  unsigned int want = 0;
  unsigned int* myctr = ctr + g * 16;

  for (int t = 0; t < TT; ++t) {
    // ---- stage h(t-1) for the whole group into LDS (device-scope loads) ----
    if (t > 0) {
      const unsigned long long* hb =
          (const unsigned long long*)(hs + ((size_t)(t - 1) * BT + bbase) * HH);
#pragma unroll
      for (int jj = 0; jj < 8; ++jj) {
        int idx = tid + 256 * jj;          // [0,2048) 8B units
        int mm = idx >> 7, cu = idx & 127; // row, 8B unit in row
        unsigned long long v =
            __hip_atomic_load(hb + mm * 128 + cu, __ATOMIC_RELAXED, __HIP_MEMORY_SCOPE_AGENT);
        int c16 = cu >> 1, half = cu & 1;
        *(unsigned long long*)&hstage[mm * 512 + ((c16 ^ (mm & 7)) << 3) + (half << 2)] = v;
      }
    } else {
#pragma unroll
      for (int jj = 0; jj < 8; ++jj)
        ((unsigned long long*)hstage)[tid + 256 * jj] = 0ull;
    }
    __syncthreads();

    // ---- fused gates GEMM: [16 batch] x [128 gate rows], K=576 (h|x) ----
    f32x4 acc0 = {0.f, 0.f, 0.f, 0.f}, acc1 = {0.f, 0.f, 0.f, 0.f};
    const unsigned short* xbase = Ax + ((size_t)t * BT + bbase + m) * 64;
#pragma unroll
    for (int s = 0; s < 18; ++s) {
      int c = 4 * s + ko;
      int cs = (c ^ (m & 7)) << 3;  // r0&7 == m&7 (32w aligned), so shared swizzle
      bf16x8 av;
      if (s < 16) {
        av = *(const bf16x8*)&hstage[m * 512 + cs];
      } else {
        av = *(const bf16x8*)(xbase + (s - 16) * 32 + (ko << 3));
      }
      bf16x8 bv0 = *(const bf16x8*)&Wl[r0 * 576 + cs];
      bf16x8 bv1 = *(const bf16x8*)&Wl[(r0 + 16) * 576 + cs];
      acc0 = __builtin_amdgcn_mfma_f32_16x16x32_bf16(av, bv0, acc0, 0, 0, 0);
      acc1 = __builtin_amdgcn_mfma_f32_16x16x32_bf16(av, bv1, acc1, 0, 0, 0);
    }
    __syncthreads();  // h-stage region dead; reuse as gates buffer
    // C/D layout: col(lane&15)=gate row-in-tile, row(ko*4+reg)=batch
    *(f32x4*)&gatesL[r0 * 20 + (ko << 2)] = acc0;
    *(f32x4*)&gatesL[(r0 + 16) * 20 + (ko << 2)] = acc1;
    __syncthreads();

    // ---- epilogue: 2 cells per thread, fp32 bias + activations, c in regs ----
    float gi0 = gatesL[(ej) * 20 + em] + bias[0][0];
    float gi1 = gatesL[(ej + 1) * 20 + em] + bias[0][1];
    float gf0 = gatesL[(32 + ej) * 20 + em] + bias[1][0];
    float gf1 = gatesL[(33 + ej) * 20 + em] + bias[1][1];
    float gg0 = gatesL[(64 + ej) * 20 + em] + bias[2][0];
    float gg1 = gatesL[(65 + ej) * 20 + em] + bias[2][1];
    float go0 = gatesL[(96 + ej) * 20 + em] + bias[3][0];
    float go1 = gatesL[(97 + ej) * 20 + em] + bias[3][1];
    float i0 = 1.f / (1.f + __expf(-gi0)), i1 = 1.f / (1.f + __expf(-gi1));
    float f0 = 1.f / (1.f + __expf(-gf0)), f1 = 1.f / (1.f + __expf(-gf1));
    float g0 = 1.f - 2.f / (1.f + __expf(2.f * gg0));
    float g1 = 1.f - 2.f / (1.f + __expf(2.f * gg1));
    float o0 = 1.f / (1.f + __expf(-go0)), o1 = 1.f / (1.f + __expf(-go1));
    c0s = f0 * c0s + i0 * g0;
    c1s = f1 * c1s + i1 * g1;
    float h0 = o0 * (1.f - 2.f / (1.f + __expf(2.f * c0s)));
    float h1 = o1 * (1.f - 2.f / (1.f + __expf(2.f * c1s)));
    unsigned int packed = (unsigned int)f2bf(h0) | ((unsigned int)f2bf(h1) << 16);
    // device-visible write-through store (cross-XCD correctness)
    __hip_atomic_store((unsigned int*)(hs + ((size_t)t * BT + bbase + em) * HH + n * 32 + ej),
                       packed, __ATOMIC_RELAXED, __HIP_MEMORY_SCOPE_AGENT);
    __syncthreads();  // all h stores drained (barrier implies vmcnt(0))
    want += GN;
    if (tid == 0) {
      __threadfence();
      __hip_atomic_fetch_add(myctr, 1u, __ATOMIC_RELEASE, __HIP_MEMORY_SCOPE_AGENT);
      if (t + 1 < TT) {
        while (__hip_atomic_load(myctr, __ATOMIC_ACQUIRE, __HIP_MEMORY_SCOPE_AGENT) < want)
          __builtin_amdgcn_s_sleep(2);
      }
    }
    __syncthreads();
  }
}

// Ax[t][b][k] = bf16(points[t][b][k]) for k<34 else 0
__global__ void __launch_bounds__(256) prep_ax(const float* __restrict__ pts,
                                               unsigned short* __restrict__ Ax) {
  size_t i = (size_t)blockIdx.x * 256 + threadIdx.x;  // [0, 512*256*64)
  int k = (int)(i & 63);
  size_t tb = i >> 6;
  float v = (k < NP) ? pts[tb * NP + k] : 0.f;
  Ax[i] = f2bf(v);
}

// logits = hs @ W_lin^T + b_lin ; softmax over 16
__global__ void __launch_bounds__(256) head_kernel(const unsigned short* __restrict__ hs,
                                                   const float* __restrict__ Wlin,
                                                   const float* __restrict__ blin,
                                                   float* __restrict__ out) {
  __shared__ float wl[16 * 513];
  __shared__ float bl[16];
  __shared__ unsigned short hl[16 * 520];
  const int tid = threadIdx.x;
  for (int i = tid; i < 16 * 512; i += 256) wl[(i >> 9) * 513 + (i & 511)] = Wlin[i];
  if (tid < 16) bl[tid] = blin[tid];
  const size_t Rb = (size_t)blockIdx.x * 16;  // 16 rows of [131072][512]
  const uint4* gsrc = (const uint4*)(hs + Rb * 512);
#pragma unroll
  for (int j = 0; j < 4; ++j) {
    int e8 = tid + 256 * j;  // uint4 index, 8 bf16 each
    uint4 v = gsrc[e8];
    int r = e8 >> 6, k = (e8 & 63) << 3;
    *(uint4*)&hl[r * 520 + k] = v;
  }
  __syncthreads();
  const int r = tid >> 4, tg = tid & 15;
  float acc = bl[tg];
  const float* wp = &wl[tg * 513];
#pragma unroll 4
  for (int k8 = 0; k8 < 64; ++k8) {
    uint4 hv = *(const uint4*)&hl[r * 520 + (k8 << 3)];
    const float* w8 = wp + (k8 << 3);
    acc += __uint_as_float(hv.x << 16) * w8[0];
    acc += __uint_as_float(hv.x & 0xffff0000u) * w8[1];
    acc += __uint_as_float(hv.y << 16) * w8[2];
    acc += __uint_as_float(hv.y & 0xffff0000u) * w8[3];
    acc += __uint_as_float(hv.z << 16) * w8[4];
    acc += __uint_as_float(hv.z & 0xffff0000u) * w8[5];
    acc += __uint_as_float(hv.w << 16) * w8[6];
    acc += __uint_as_float(hv.w & 0xffff0000u) * w8[7];
  }
  float mx = acc;
#pragma unroll
  for (int d = 8; d; d >>= 1) mx = fmaxf(mx, __shfl_xor(mx, d, 16));
  float e = __expf(acc - mx);
  float sm = e;
#pragma unroll
  for (int d = 8; d; d >>= 1) sm += __shfl_xor(sm, d, 16);
  out[Rb * 16 + tid] = e / sm;
}

extern "C" void kernel_launch(void* const* d_in, const int* in_sizes, int n_in,
                              void* d_out, int out_size, void* d_ws, size_t ws_size,
                              hipStream_t stream) {
  (void)in_sizes; (void)n_in; (void)out_size; (void)ws_size;
  const float* pts  = (const float*)d_in[0];
  const float* Wih  = (const float*)d_in[1];
  const float* Whh  = (const float*)d_in[2];
  const float* bih  = (const float*)d_in[3];
  const float* bhh  = (const float*)d_in[4];
  const float* Wlin = (const float*)d_in[5];
  const float* blin = (const float*)d_in[6];
  float* out = (float*)d_out;
  char* ws = (char*)d_ws;
  // ws layout: hs 134217728 B | Ax 16777216 B | ctr 1024 B  (~151 MB)
  unsigned short* hs = (unsigned short*)ws;
  unsigned short* Ax = (unsigned short*)(ws + 134217728);
  unsigned int* ctr  = (unsigned int*)(ws + 150994944);

  hipMemsetAsync(ctr, 0, 1024, stream);
  prep_ax<<<32768, 256, 0, stream>>>(pts, Ax);
  // opt-in to full 160 KiB LDS (ignore error if runtime doesn't need it)
  (void)hipFuncSetAttribute((const void*)lstm_coop,
                            hipFuncAttributeMaxDynamicSharedMemorySize, 163840);
  void* args[7];
  args[0] = (void*)&Whh; args[1] = (void*)&Wih; args[2] = (void*)&bih;
  args[3] = (void*)&bhh; args[4] = (void*)&Ax;  args[5] = (void*)&hs;
  args[6] = (void*)&ctr;
  hipLaunchCooperativeKernel((void*)lstm_coop, dim3(GB * GN), dim3(256), args, 163840, stream);
  head_kernel<<<8192, 256, 0, stream>>>(hs, Wlin, blin, out);
}

// Round 2
// 4159.913 us; speedup vs baseline: 1.4476x; 1.4476x over previous
//
#include <hip/hip_runtime.h>
#include <hip/hip_bf16.h>

// LSTM T=512 B=256 NP=34 H=512 NT=16.
// 16 groups (16 batches each) x 16 blocks (32 h-cols each, all 4 gates).
// W_hh|W_ih slice resident in LDS bf16, K = 512(h)+34(x)+pad = 576.
// Per step: h exchanged via relaxed agent-scope atomics (coherent point = L3),
// per-producer flag stores (release) + relaxed polling + one acquire fence.
#define TT 512
#define BT 256
#define NP 34
#define HH 512
#define GB 16
#define GN 16

typedef short bf16x8 __attribute__((ext_vector_type(8)));
typedef float f32x4 __attribute__((ext_vector_type(4)));

static __device__ __forceinline__ unsigned short f2bf(float x) {
  unsigned int u = __float_as_uint(x);
  unsigned int r = (u + 0x7fffu + ((u >> 16) & 1u)) >> 16;
  return (unsigned short)r;
}

// LDS map (163840 B dynamic):
//   [0, 147456)        W slice bf16 [128 rows][576], 16B-chunk swizzle: phys_chunk = c ^ (r&7)
//   [147456, 163840)   phase-aliased: h-stage bf16 [16][512] (same swizzle) during MFMA;
//                      gates f32 [128][20] during epilogue.
__global__ void __launch_bounds__(256, 1) lstm_coop(
    const float* __restrict__ Whh, const float* __restrict__ Wih,
    const float* __restrict__ bih, const float* __restrict__ bhh,
    const unsigned short* __restrict__ Ax,  // [T][256][64] bf16 bits: [points(34), 0...]
    unsigned short* hs,                     // [T][256][512] bf16 bits
    unsigned int* flags)                    // [16 groups][16 producers] u32
{
  extern __shared__ char smem[];
  unsigned short* Wl = (unsigned short*)smem;
  unsigned short* hstage = (unsigned short*)(smem + 147456);
  float* gatesL = (float*)(smem + 147456);

  const int tid = threadIdx.x;
  const int g = blockIdx.x & 15;   // group
  const int n = blockIdx.x >> 4;   // block-in-group -> h-cols [n*32, n*32+32)
  const int bbase = g * 16;        // batch base

  // ---- init resident W slice (swizzled) ----
  for (int idx = tid; idx < 128 * 576; idx += 256) {
    int r = idx / 576, k = idx - r * 576;
    int grow = (r >> 5) * 512 + n * 32 + (r & 31);  // gate q=r>>5 (i,f,g,o), hcol j=r&31
    float v = 0.f;
    if (k < 512) v = Whh[(size_t)grow * 512 + k];
    else if (k < 546) v = Wih[grow * 34 + (k - 512)];
    int c = k >> 3, within = k & 7;
    Wl[r * 576 + ((c ^ (r & 7)) << 3) + within] = f2bf(v);
  }
  // epilogue cell assignment: thread -> (batch em, hcols ej, ej+1); biases exact in regs
  const int em = tid >> 4;
  const int ej = (tid & 15) << 1;
  float bias[4][2];
#pragma unroll
  for (int q = 0; q < 4; ++q) {
    int gr = q * 512 + n * 32 + ej;
    bias[q][0] = bih[gr] + bhh[gr];
    bias[q][1] = bih[gr + 1] + bhh[gr + 1];
  }
  const int lane = tid & 63;
  const int w = tid >> 6;
  const int m = lane & 15;   // A: batch row; B/D: col within tile
  const int ko = lane >> 4;
  const int r0 = 32 * w + m; // wave w covers W rows [32w,32w+32) = gate q=w
  float c0s = 0.f, c1s = 0.f;
  unsigned int* gflags = flags + g * 16;
  unsigned int* myflag = gflags + n;

  for (int t = 0; t < TT; ++t) {
    // prefetch this step's x fragments (independent of flags)
    const unsigned short* xbase = Ax + ((size_t)t * BT + bbase + m) * 64;
    bf16x8 xv0 = *(const bf16x8*)(xbase + (ko << 3));
    bf16x8 xv1 = *(const bf16x8*)(xbase + 32 + (ko << 3));

    if (t > 0) {
      // ---- wait for all 16 producers of h(t-1): relaxed poll, then one acq fence
      if (tid < 16) {
        const unsigned int tgt = (unsigned int)t;
        unsigned int* fp = gflags + tid;
        int guard = 0;
        while (__hip_atomic_load(fp, __ATOMIC_RELAXED, __HIP_MEMORY_SCOPE_AGENT) < tgt) {
          __builtin_amdgcn_s_sleep(1);
          if (++guard > (1 << 23)) break;  // bounded spin (deadlock guard)
        }
      }
      if (tid < 64) __builtin_amdgcn_fence(__ATOMIC_ACQUIRE, "agent");
    }
    __syncthreads();

    // ---- stage h(t-1) for the whole group into LDS (agent-scope loads) ----
    if (t > 0) {
      const unsigned long long* hb =
          (const unsigned long long*)(hs + ((size_t)(t - 1) * BT + bbase) * HH);
#pragma unroll
      for (int jj = 0; jj < 8; ++jj) {
        int idx = tid + 256 * jj;          // [0,2048) 8B units
        int mm = idx >> 7, cu = idx & 127; // row, 8B unit in row
        unsigned long long v =
            __hip_atomic_load(hb + mm * 128 + cu, __ATOMIC_RELAXED, __HIP_MEMORY_SCOPE_AGENT);
        int c16 = cu >> 1, half = cu & 1;
        *(unsigned long long*)&hstage[mm * 512 + ((c16 ^ (mm & 7)) << 3) + (half << 2)] = v;
      }
    } else {
#pragma unroll
      for (int jj = 0; jj < 8; ++jj)
        ((unsigned long long*)hstage)[tid + 256 * jj] = 0ull;
    }
    __syncthreads();

    // ---- fused gates GEMM: [16 batch] x [128 gate rows], K=576 (h|x) ----
    f32x4 acc0 = {0.f, 0.f, 0.f, 0.f}, acc1 = {0.f, 0.f, 0.f, 0.f};
#pragma unroll
    for (int s = 0; s < 18; ++s) {
      int c = 4 * s + ko;
      int cs = (c ^ (m & 7)) << 3;  // r0&7 == m&7 (32w aligned), so shared swizzle
      bf16x8 av;
      if (s < 16) {
        av = *(const bf16x8*)&hstage[m * 512 + cs];
      } else {
        av = (s == 16) ? xv0 : xv1;
      }
      bf16x8 bv0 = *(const bf16x8*)&Wl[r0 * 576 + cs];
      bf16x8 bv1 = *(const bf16x8*)&Wl[(r0 + 16) * 576 + cs];
      acc0 = __builtin_amdgcn_mfma_f32_16x16x32_bf16(av, bv0, acc0, 0, 0, 0);
      acc1 = __builtin_amdgcn_mfma_f32_16x16x32_bf16(av, bv1, acc1, 0, 0, 0);
    }
    __syncthreads();  // h-stage region dead; reuse as gates buffer
    // C/D layout: col(lane&15)=gate row-in-tile, row(ko*4+reg)=batch
    *(f32x4*)&gatesL[r0 * 20 + (ko << 2)] = acc0;
    *(f32x4*)&gatesL[(r0 + 16) * 20 + (ko << 2)] = acc1;
    __syncthreads();

    // ---- epilogue: 2 cells per thread, fp32 bias + activations, c in regs ----
    float gi0 = gatesL[(ej) * 20 + em] + bias[0][0];
    float gi1 = gatesL[(ej + 1) * 20 + em] + bias[0][1];
    float gf0 = gatesL[(32 + ej) * 20 + em] + bias[1][0];
    float gf1 = gatesL[(33 + ej) * 20 + em] + bias[1][1];
    float gg0 = gatesL[(64 + ej) * 20 + em] + bias[2][0];
    float gg1 = gatesL[(65 + ej) * 20 + em] + bias[2][1];
    float go0 = gatesL[(96 + ej) * 20 + em] + bias[3][0];
    float go1 = gatesL[(97 + ej) * 20 + em] + bias[3][1];
    float i0 = 1.f / (1.f + __expf(-gi0)), i1 = 1.f / (1.f + __expf(-gi1));
    float f0 = 1.f / (1.f + __expf(-gf0)), f1 = 1.f / (1.f + __expf(-gf1));
    float g0 = 1.f - 2.f / (1.f + __expf(2.f * gg0));
    float g1 = 1.f - 2.f / (1.f + __expf(2.f * gg1));
    float o0 = 1.f / (1.f + __expf(-go0)), o1 = 1.f / (1.f + __expf(-go1));
    c0s = f0 * c0s + i0 * g0;
    c1s = f1 * c1s + i1 * g1;
    float h0 = o0 * (1.f - 2.f / (1.f + __expf(2.f * c0s)));
    float h1 = o1 * (1.f - 2.f / (1.f + __expf(2.f * c1s)));
    unsigned int packed = (unsigned int)f2bf(h0) | ((unsigned int)f2bf(h1) << 16);
    // agent-scope store: bypasses L1/L2, lands at coherent point (cross-XCD safe)
    __hip_atomic_store((unsigned int*)(hs + ((size_t)t * BT + bbase + em) * HH + n * 32 + ej),
                       packed, __ATOMIC_RELAXED, __HIP_MEMORY_SCOPE_AGENT);
    __syncthreads();  // drains vmcnt(0): all h stores complete at coherent point
    if (tid == 0) {
      // release store (wbl2 is cheap: our L2 is clean) publishes h(t)
      __hip_atomic_store(myflag, (unsigned int)(t + 1), __ATOMIC_RELEASE,
                         __HIP_MEMORY_SCOPE_AGENT);
    }
  }
}

// Ax[t][b][k] = bf16(points[t][b][k]) for k<34 else 0
__global__ void __launch_bounds__(256) prep_ax(const float* __restrict__ pts,
                                               unsigned short* __restrict__ Ax) {
  size_t i = (size_t)blockIdx.x * 256 + threadIdx.x;  // [0, 512*256*64)
  int k = (int)(i & 63);
  size_t tb = i >> 6;
  float v = (k < NP) ? pts[tb * NP + k] : 0.f;
  Ax[i] = f2bf(v);
}

// logits = hs @ W_lin^T + b_lin ; softmax over 16
__global__ void __launch_bounds__(256) head_kernel(const unsigned short* __restrict__ hs,
                                                   const float* __restrict__ Wlin,
                                                   const float* __restrict__ blin,
                                                   float* __restrict__ out) {
  __shared__ float wl[16 * 513];
  __shared__ float bl[16];
  __shared__ unsigned short hl[16 * 520];
  const int tid = threadIdx.x;
  for (int i = tid; i < 16 * 512; i += 256) wl[(i >> 9) * 513 + (i & 511)] = Wlin[i];
  if (tid < 16) bl[tid] = blin[tid];
  const size_t Rb = (size_t)blockIdx.x * 16;  // 16 rows of [131072][512]
  const uint4* gsrc = (const uint4*)(hs + Rb * 512);
#pragma unroll
  for (int j = 0; j < 4; ++j) {
    int e8 = tid + 256 * j;  // uint4 index, 8 bf16 each
    uint4 v = gsrc[e8];
    int r = e8 >> 6, k = (e8 & 63) << 3;
    *(uint4*)&hl[r * 520 + k] = v;
  }
  __syncthreads();
  const int r = tid >> 4, tg = tid & 15;
  float acc = bl[tg];
  const float* wp = &wl[tg * 513];
#pragma unroll 4
  for (int k8 = 0; k8 < 64; ++k8) {
    uint4 hv = *(const uint4*)&hl[r * 520 + (k8 << 3)];
    const float* w8 = wp + (k8 << 3);
    acc += __uint_as_float(hv.x << 16) * w8[0];
    acc += __uint_as_float(hv.x & 0xffff0000u) * w8[1];
    acc += __uint_as_float(hv.y << 16) * w8[2];
    acc += __uint_as_float(hv.y & 0xffff0000u) * w8[3];
    acc += __uint_as_float(hv.z << 16) * w8[4];
    acc += __uint_as_float(hv.z & 0xffff0000u) * w8[5];
    acc += __uint_as_float(hv.w << 16) * w8[6];
    acc += __uint_as_float(hv.w & 0xffff0000u) * w8[7];
  }
  float mx = acc;
#pragma unroll
  for (int d = 8; d; d >>= 1) mx = fmaxf(mx, __shfl_xor(mx, d, 16));
  float e = __expf(acc - mx);
  float sm = e;
#pragma unroll
  for (int d = 8; d; d >>= 1) sm += __shfl_xor(sm, d, 16);
  out[Rb * 16 + tid] = e / sm;
}

extern "C" void kernel_launch(void* const* d_in, const int* in_sizes, int n_in,
                              void* d_out, int out_size, void* d_ws, size_t ws_size,
                              hipStream_t stream) {
  (void)in_sizes; (void)n_in; (void)out_size; (void)ws_size;
  const float* pts  = (const float*)d_in[0];
  const float* Wih  = (const float*)d_in[1];
  const float* Whh  = (const float*)d_in[2];
  const float* bih  = (const float*)d_in[3];
  const float* bhh  = (const float*)d_in[4];
  const float* Wlin = (const float*)d_in[5];
  const float* blin = (const float*)d_in[6];
  float* out = (float*)d_out;
  char* ws = (char*)d_ws;
  // ws layout: hs 134217728 B | Ax 16777216 B | flags 1024 B  (~151 MB)
  unsigned short* hs = (unsigned short*)ws;
  unsigned short* Ax = (unsigned short*)(ws + 134217728);
  unsigned int* flags = (unsigned int*)(ws + 150994944);

  hipMemsetAsync(flags, 0, 1024, stream);
  prep_ax<<<32768, 256, 0, stream>>>(pts, Ax);
  (void)hipFuncSetAttribute((const void*)lstm_coop,
                            hipFuncAttributeMaxDynamicSharedMemorySize, 163840);
  void* args[7];
  args[0] = (void*)&Whh; args[1] = (void*)&Wih; args[2] = (void*)&bih;
  args[3] = (void*)&bhh; args[4] = (void*)&Ax;  args[5] = (void*)&hs;
  args[6] = (void*)&flags;
  hipLaunchCooperativeKernel((void*)lstm_coop, dim3(GB * GN), dim3(256), args, 163840, stream);
  head_kernel<<<8192, 256, 0, stream>>>(hs, Wlin, blin, out);
}

// Round 3
// 2286.334 us; speedup vs baseline: 2.6338x; 1.8195x over previous
//
#include <hip/hip_runtime.h>
#include <hip/hip_bf16.h>

// LSTM T=512 B=256 NP=34 H=512 NT=16.
// 16 groups (16 batches each) x 16 blocks (32 h-cols each, all 4 gates).
// W_hh|W_ih slice resident in LDS bf16, K = 512(h)+34(x)+pad = 576.
// Sync scheme (R3): NO flags/fences. hs is pre-memset to 0xAAAAAAAA; every
// h dword is written once by a relaxed agent-scope store; consumers poll the
// exact dwords they need until != sentinel (the successful poll IS the data
// load). Per-dword data dependency replaces all release/acquire machinery.
#define TT 512
#define BT 256
#define NP 34
#define HH 512
#define GB 16
#define GN 16
#define SENT 0xAAAAAAAAu

typedef short bf16x8 __attribute__((ext_vector_type(8)));
typedef float f32x4 __attribute__((ext_vector_type(4)));

static __device__ __forceinline__ unsigned short f2bf(float x) {
  unsigned int u = __float_as_uint(x);
  unsigned int r = (u + 0x7fffu + ((u >> 16) & 1u)) >> 16;
  return (unsigned short)r;
}

// LDS map (163840 B dynamic):
//   [0, 147456)        W slice bf16 [128 rows][576], 16B-chunk swizzle: phys_chunk = c ^ (r&7)
//   [147456, 163840)   phase-aliased: h-stage bf16 [16][512] (same swizzle) during MFMA;
//                      gates f32 [128][20] during epilogue.
__global__ void __launch_bounds__(256, 1) lstm_coop(
    const float* __restrict__ Whh, const float* __restrict__ Wih,
    const float* __restrict__ bih, const float* __restrict__ bhh,
    const unsigned short* __restrict__ Ax,  // [T][256][64] bf16 bits: [points(34), 0...]
    unsigned short* hs)                     // [T][256][512] bf16 bits, pre-set to SENT
{
  extern __shared__ char smem[];
  unsigned short* Wl = (unsigned short*)smem;
  unsigned short* hstage = (unsigned short*)(smem + 147456);
  float* gatesL = (float*)(smem + 147456);

  const int tid = threadIdx.x;
  const int g = blockIdx.x & 15;   // group
  const int n = blockIdx.x >> 4;   // block-in-group -> h-cols [n*32, n*32+32)
  const int bbase = g * 16;        // batch base

  // ---- init resident W slice (swizzled) ----
  for (int idx = tid; idx < 128 * 576; idx += 256) {
    int r = idx / 576, k = idx - r * 576;
    int grow = (r >> 5) * 512 + n * 32 + (r & 31);  // gate q=r>>5 (i,f,g,o), hcol j=r&31
    float v = 0.f;
    if (k < 512) v = Whh[(size_t)grow * 512 + k];
    else if (k < 546) v = Wih[grow * 34 + (k - 512)];
    int c = k >> 3, within = k & 7;
    Wl[r * 576 + ((c ^ (r & 7)) << 3) + within] = f2bf(v);
  }
  // epilogue cell assignment: thread -> (batch em, hcols ej, ej+1); biases exact in regs
  const int em = tid >> 4;
  const int ej = (tid & 15) << 1;
  float bias[4][2];
#pragma unroll
  for (int q = 0; q < 4; ++q) {
    int gr = q * 512 + n * 32 + ej;
    bias[q][0] = bih[gr] + bhh[gr];
    bias[q][1] = bih[gr + 1] + bhh[gr + 1];
  }
  const int lane = tid & 63;
  const int w = tid >> 6;
  const int m = lane & 15;   // A: batch row; B/D: col within tile
  const int ko = lane >> 4;
  const int r0 = 32 * w + m; // wave w covers W rows [32w,32w+32) = gate q=w
  float c0s = 0.f, c1s = 0.f;

  for (int t = 0; t < TT; ++t) {
    // prefetch this step's x fragments (independent of h)
    const unsigned short* xbase = Ax + ((size_t)t * BT + bbase + m) * 64;
    bf16x8 xv0 = *(const bf16x8*)(xbase + (ko << 3));
    bf16x8 xv1 = *(const bf16x8*)(xbase + 32 + (ko << 3));

    // ---- acquire h(t-1): poll own 8 u64 units until non-sentinel ----
    unsigned long long hv[8];
    if (t > 0) {
      const unsigned long long* hb =
          (const unsigned long long*)(hs + ((size_t)(t - 1) * BT + bbase) * HH);
      unsigned int vm = 0;
      int guard = 0;
      while (vm != 0xffu) {
#pragma unroll
        for (int jj = 0; jj < 8; ++jj) {
          if (!((vm >> jj) & 1u)) {
            unsigned long long x = __hip_atomic_load(hb + jj * 256 + tid,
                                                     __ATOMIC_RELAXED,
                                                     __HIP_MEMORY_SCOPE_AGENT);
            if ((unsigned int)x != SENT && (unsigned int)(x >> 32) != SENT) {
              hv[jj] = x;
              vm |= (1u << jj);
            }
          }
        }
        if (vm == 0xffu) break;
        if (++guard > (1 << 20)) break;  // deadlock guard
        __builtin_amdgcn_s_sleep(1);
      }
    } else {
#pragma unroll
      for (int jj = 0; jj < 8; ++jj) hv[jj] = 0ull;
    }
    // stage into LDS (swizzled)
#pragma unroll
    for (int jj = 0; jj < 8; ++jj) {
      int idx = jj * 256 + tid;          // [0,2048) 8B units
      int mm = idx >> 7, cu = idx & 127; // row, 8B unit in row
      int c16 = cu >> 1, half = cu & 1;
      *(unsigned long long*)&hstage[mm * 512 + ((c16 ^ (mm & 7)) << 3) + (half << 2)] = hv[jj];
    }
    __syncthreads();  // B1: hstage visible

    // ---- fused gates GEMM: [16 batch] x [128 gate rows], K=576 (h|x) ----
    f32x4 acc0 = {0.f, 0.f, 0.f, 0.f}, acc1 = {0.f, 0.f, 0.f, 0.f};
#pragma unroll
    for (int s = 0; s < 18; ++s) {
      int c = 4 * s + ko;
      int cs = (c ^ (m & 7)) << 3;  // r0&7 == m&7 (32w aligned), so shared swizzle
      bf16x8 av;
      if (s < 16) {
        av = *(const bf16x8*)&hstage[m * 512 + cs];
      } else {
        av = (s == 16) ? xv0 : xv1;
      }
      bf16x8 bv0 = *(const bf16x8*)&Wl[r0 * 576 + cs];
      bf16x8 bv1 = *(const bf16x8*)&Wl[(r0 + 16) * 576 + cs];
      acc0 = __builtin_amdgcn_mfma_f32_16x16x32_bf16(av, bv0, acc0, 0, 0, 0);
      acc1 = __builtin_amdgcn_mfma_f32_16x16x32_bf16(av, bv1, acc1, 0, 0, 0);
    }
    __syncthreads();  // B2: hstage reads done; region reused as gates buffer
    // C/D layout: col(lane&15)=gate row-in-tile, row(ko*4+reg)=batch
    *(f32x4*)&gatesL[r0 * 20 + (ko << 2)] = acc0;
    *(f32x4*)&gatesL[(r0 + 16) * 20 + (ko << 2)] = acc1;
    __syncthreads();  // B3: gates visible

    // ---- epilogue: 2 cells per thread ----
    float gi0 = gatesL[(ej) * 20 + em] + bias[0][0];
    float gi1 = gatesL[(ej + 1) * 20 + em] + bias[0][1];
    float gf0 = gatesL[(32 + ej) * 20 + em] + bias[1][0];
    float gf1 = gatesL[(33 + ej) * 20 + em] + bias[1][1];
    float gg0 = gatesL[(64 + ej) * 20 + em] + bias[2][0];
    float gg1 = gatesL[(65 + ej) * 20 + em] + bias[2][1];
    float go0 = gatesL[(96 + ej) * 20 + em] + bias[3][0];
    float go1 = gatesL[(97 + ej) * 20 + em] + bias[3][1];
    __syncthreads();  // B4: gatesL reads done; next iter may overwrite stage region

    float i0 = 1.f / (1.f + __expf(-gi0)), i1 = 1.f / (1.f + __expf(-gi1));
    float f0 = 1.f / (1.f + __expf(-gf0)), f1 = 1.f / (1.f + __expf(-gf1));
    float g0 = 1.f - 2.f / (1.f + __expf(2.f * gg0));
    float g1 = 1.f - 2.f / (1.f + __expf(2.f * gg1));
    float o0 = 1.f / (1.f + __expf(-go0)), o1 = 1.f / (1.f + __expf(-go1));
    c0s = f0 * c0s + i0 * g0;
    c1s = f1 * c1s + i1 * g1;
    float h0 = o0 * (1.f - 2.f / (1.f + __expf(2.f * c0s)));
    float h1 = o1 * (1.f - 2.f / (1.f + __expf(2.f * c1s)));
    unsigned int packed = (unsigned int)f2bf(h0) | ((unsigned int)f2bf(h1) << 16);
    // relaxed agent-scope store: write-through to coherent point; consumers
    // self-validate per dword, so no drain/release needed — fire and proceed.
    __hip_atomic_store((unsigned int*)(hs + ((size_t)t * BT + bbase + em) * HH + n * 32 + ej),
                       packed, __ATOMIC_RELAXED, __HIP_MEMORY_SCOPE_AGENT);
  }
}

// Ax[t][b][k] = bf16(points[t][b][k]) for k<34 else 0
__global__ void __launch_bounds__(256) prep_ax(const float* __restrict__ pts,
                                               unsigned short* __restrict__ Ax) {
  size_t i = (size_t)blockIdx.x * 256 + threadIdx.x;  // [0, 512*256*64)
  int k = (int)(i & 63);
  size_t tb = i >> 6;
  float v = (k < NP) ? pts[tb * NP + k] : 0.f;
  Ax[i] = f2bf(v);
}

// logits = hs @ W_lin^T + b_lin ; softmax over 16
__global__ void __launch_bounds__(256) head_kernel(const unsigned short* __restrict__ hs,
                                                   const float* __restrict__ Wlin,
                                                   const float* __restrict__ blin,
                                                   float* __restrict__ out) {
  __shared__ float wl[16 * 513];
  __shared__ float bl[16];
  __shared__ unsigned short hl[16 * 520];
  const int tid = threadIdx.x;
  for (int i = tid; i < 16 * 512; i += 256) wl[(i >> 9) * 513 + (i & 511)] = Wlin[i];
  if (tid < 16) bl[tid] = blin[tid];
  const size_t Rb = (size_t)blockIdx.x * 16;  // 16 rows of [131072][512]
  const uint4* gsrc = (const uint4*)(hs + Rb * 512);
#pragma unroll
  for (int j = 0; j < 4; ++j) {
    int e8 = tid + 256 * j;  // uint4 index, 8 bf16 each
    uint4 v = gsrc[e8];
    int r = e8 >> 6, k = (e8 & 63) << 3;
    *(uint4*)&hl[r * 520 + k] = v;
  }
  __syncthreads();
  const int r = tid >> 4, tg = tid & 15;
  float acc = bl[tg];
  const float* wp = &wl[tg * 513];
#pragma unroll 4
  for (int k8 = 0; k8 < 64; ++k8) {
    uint4 hv = *(const uint4*)&hl[r * 520 + (k8 << 3)];
    const float* w8 = wp + (k8 << 3);
    acc += __uint_as_float(hv.x << 16) * w8[0];
    acc += __uint_as_float(hv.x & 0xffff0000u) * w8[1];
    acc += __uint_as_float(hv.y << 16) * w8[2];
    acc += __uint_as_float(hv.y & 0xffff0000u) * w8[3];
    acc += __uint_as_float(hv.z << 16) * w8[4];
    acc += __uint_as_float(hv.z & 0xffff0000u) * w8[5];
    acc += __uint_as_float(hv.w << 16) * w8[6];
    acc += __uint_as_float(hv.w & 0xffff0000u) * w8[7];
  }
  float mx = acc;
#pragma unroll
  for (int d = 8; d; d >>= 1) mx = fmaxf(mx, __shfl_xor(mx, d, 16));
  float e = __expf(acc - mx);
  float sm = e;
#pragma unroll
  for (int d = 8; d; d >>= 1) sm += __shfl_xor(sm, d, 16);
  out[Rb * 16 + tid] = e / sm;
}

extern "C" void kernel_launch(void* const* d_in, const int* in_sizes, int n_in,
                              void* d_out, int out_size, void* d_ws, size_t ws_size,
                              hipStream_t stream) {
  (void)in_sizes; (void)n_in; (void)out_size; (void)ws_size;
  const float* pts  = (const float*)d_in[0];
  const float* Wih  = (const float*)d_in[1];
  const float* Whh  = (const float*)d_in[2];
  const float* bih  = (const float*)d_in[3];
  const float* bhh  = (const float*)d_in[4];
  const float* Wlin = (const float*)d_in[5];
  const float* blin = (const float*)d_in[6];
  float* out = (float*)d_out;
  char* ws = (char*)d_ws;
  // ws layout: hs 134217728 B | Ax 16777216 B
  unsigned short* hs = (unsigned short*)ws;
  unsigned short* Ax = (unsigned short*)(ws + 134217728);

  // sentinel-fill hs (self-validating exchange protocol needs every launch)
  hipMemsetAsync(hs, 0xAA, 134217728, stream);
  prep_ax<<<32768, 256, 0, stream>>>(pts, Ax);
  (void)hipFuncSetAttribute((const void*)lstm_coop,
                            hipFuncAttributeMaxDynamicSharedMemorySize, 163840);
  void* args[6];
  args[0] = (void*)&Whh; args[1] = (void*)&Wih; args[2] = (void*)&bih;
  args[3] = (void*)&bhh; args[4] = (void*)&Ax;  args[5] = (void*)&hs;
  hipLaunchCooperativeKernel((void*)lstm_coop, dim3(GB * GN), dim3(256), args, 163840, stream);
  head_kernel<<<8192, 256, 0, stream>>>(hs, Wlin, blin, out);
}